// Round 5
// baseline (242.598 us; speedup 1.0000x reference)
//
#include <hip/hip_runtime.h>

#define NN     100000
#define DEG    16
#define IN_F   128
#define OUT_F  32
#define KK     4
#define JDIM   (KK * OUT_F)   // 128

typedef __attribute__((ext_vector_type(8))) short short8;     // 8 bf16 = 4 VGPR
typedef __attribute__((ext_vector_type(4))) short short4v;    // 4 bf16 = 8 B
typedef __attribute__((ext_vector_type(4))) float floatx4;    // MFMA C/D

// fp32 -> bf16 bits, round-to-nearest-even (inputs are finite normals)
static __device__ __forceinline__ unsigned short f2bf(float f) {
  unsigned int u = __builtin_bit_cast(unsigned int, f);
  u += 0x7fffu + ((u >> 16) & 1u);
  return (unsigned short)(u >> 16);
}

// ---------------------------------------------------------------------------
// Kernel P: fc_w (fp32, [128][128]) -> bf16 in MFMA A-fragment order.
// Slot g = (s*8+t)*64 + q*16 + c holds fc_w[t*16+c][s*32+q*8 .. +7]:
// kernel A's (s,t) fragment load is wcvt + ((s*8+t)*64 + lane)*8, coalesced.
// ---------------------------------------------------------------------------
__global__ __launch_bounds__(256) void gmm_cvt_w(
    const float* __restrict__ fc_w, unsigned short* __restrict__ wcvt)
{
  const int g = blockIdx.x * 256 + threadIdx.x;   // 0..2047
  const int c = g & 15, q = (g >> 4) & 3, t = (g >> 6) & 7, s = g >> 9;
  const float* src = fc_w + (size_t)(t * 16 + c) * IN_F + s * 32 + q * 8;
  const float4 f0 = *(const float4*)src;
  const float4 f1 = *(const float4*)(src + 4);
  short8 v;
  v[0] = (short)f2bf(f0.x); v[1] = (short)f2bf(f0.y);
  v[2] = (short)f2bf(f0.z); v[3] = (short)f2bf(f0.w);
  v[4] = (short)f2bf(f1.x); v[5] = (short)f2bf(f1.y);
  v[6] = (short)f2bf(f1.z); v[7] = (short)f2bf(f1.w);
  *(short8*)(wcvt + (size_t)g * 8) = v;
}

// ---------------------------------------------------------------------------
// Kernel A (MFMA): nf_bf16[m][j] = sum_i feat[m][i] * fc_w[j][i]
// One wave per 32-node m-tile (two 16-node feat B-frags share each W A-frag:
// halves W re-reads, 64 MFMA/wave). A = W tile (M=j), B = feat^T (N=node).
// D: row = j-local = q*4+r (contiguous j), col = node -> 8 B bf16x4 stores.
// ---------------------------------------------------------------------------
__global__ __launch_bounds__(256) void gmm_fc_mfma(
    const float* __restrict__ feat, const unsigned short* __restrict__ wcvt,
    unsigned short* __restrict__ nf)
{
  const int lane = threadIdx.x & 63;
  const int wv   = threadIdx.x >> 6;
  const int tile = blockIdx.x * 4 + wv;            // 32-node tile id
  if (tile * 32 >= NN) return;                     // NN % 32 == 0: full tiles
  const int m0 = tile * 32;
  const int c  = lane & 15;
  const int q  = lane >> 4;

  floatx4 acc[2][8];
#pragma unroll
  for (int g = 0; g < 2; ++g)
#pragma unroll
    for (int t = 0; t < 8; ++t) acc[g][t] = (floatx4){0.f, 0.f, 0.f, 0.f};

  const float*  frow0 = feat + (size_t)(m0 + c) * IN_F + q * 8;
  const float*  frow1 = frow0 + (size_t)16 * IN_F;
  const short8* wbase = (const short8*)wcvt;

#pragma unroll
  for (int s = 0; s < 4; ++s) {
    short8 bv0, bv1;
    {
      const float4 b0 = *(const float4*)(frow0 + s * 32);
      const float4 b1 = *(const float4*)(frow0 + s * 32 + 4);
      bv0[0] = (short)f2bf(b0.x); bv0[1] = (short)f2bf(b0.y);
      bv0[2] = (short)f2bf(b0.z); bv0[3] = (short)f2bf(b0.w);
      bv0[4] = (short)f2bf(b1.x); bv0[5] = (short)f2bf(b1.y);
      bv0[6] = (short)f2bf(b1.z); bv0[7] = (short)f2bf(b1.w);
    }
    {
      const float4 b0 = *(const float4*)(frow1 + s * 32);
      const float4 b1 = *(const float4*)(frow1 + s * 32 + 4);
      bv1[0] = (short)f2bf(b0.x); bv1[1] = (short)f2bf(b0.y);
      bv1[2] = (short)f2bf(b0.z); bv1[3] = (short)f2bf(b0.w);
      bv1[4] = (short)f2bf(b1.x); bv1[5] = (short)f2bf(b1.y);
      bv1[6] = (short)f2bf(b1.z); bv1[7] = (short)f2bf(b1.w);
    }
#pragma unroll
    for (int t = 0; t < 8; ++t) {
      const short8 av = wbase[(s * 8 + t) * 64 + lane];
      acc[0][t] = __builtin_amdgcn_mfma_f32_16x16x32_bf16(av, bv0, acc[0][t], 0, 0, 0);
      acc[1][t] = __builtin_amdgcn_mfma_f32_16x16x32_bf16(av, bv1, acc[1][t], 0, 0, 0);
    }
  }

  // D element r of acc[g][t]: node = m0+g*16+c, j = t*16 + q*4 + r
#pragma unroll
  for (int g = 0; g < 2; ++g) {
#pragma unroll
    for (int t = 0; t < 8; ++t) {
      short4v p;
      p[0] = (short)f2bf(acc[g][t][0]); p[1] = (short)f2bf(acc[g][t][1]);
      p[2] = (short)f2bf(acc[g][t][2]); p[3] = (short)f2bf(acc[g][t][3]);
      *(short4v*)(nf + (size_t)(m0 + g * 16 + c) * JDIM + t * 16 + q * 4) = p;
    }
  }
}

// ---------------------------------------------------------------------------
// Kernel B: out[i][f] = bias[f] + sum_{e in row i} sum_k w[e,k]*nf[src_e][k*32+f]
// 128 thr = 32 nodes x 4 lanes (8 feats each, uint4 gathers, 4 lanes x 16B =
// 64B line per (src,k)). 512 edges staged in LDS (10 KB). Edge order rotated
// by local node -> conflict-free. TLP-first: launch_bounds(128,8) targets
// <=64 VGPR -> 8 waves/SIMD, 16 blocks/CU (LDS exactly full at 160 KB).
// Per-wave ILP deliberately NOT pipelined (round-4 post-mortem: +20 VGPR
// cost -> occupancy 26->18% -> net regression).
// ---------------------------------------------------------------------------
__global__ __launch_bounds__(128, 8) void gmm_edge_gather(
    const int* __restrict__ rowptr, const int* __restrict__ colind,
    const int* __restrict__ permute, const float* __restrict__ pseudo,
    const float* __restrict__ mu, const float* __restrict__ inv_sigma,
    const float* __restrict__ bias, const unsigned short* __restrict__ nf,
    float* __restrict__ out)
{
  __shared__ int   s_src[512];      // 2 KB
  __shared__ float s_w[512][4];     // 8 KB

  const int tid   = threadIdx.x;
  const int node0 = blockIdx.x * 32;    // NN % 32 == 0: all blocks full

  float mx[KK], my[KK], sx[KK], sy[KK];
#pragma unroll
  for (int k = 0; k < KK; ++k) {
    mx[k] = mu[k * 2 + 0];
    my[k] = mu[k * 2 + 1];
    sx[k] = inv_sigma[k * 2 + 0];
    sy[k] = inv_sigma[k * 2 + 1];
  }

  // stage 512 edges (4 per thread): src id + 4 gaussian weights
#pragma unroll
  for (int r = 0; r < 4; ++r) {
    const int t  = tid + r * 128;
    const int nl = t >> 4;
    const int e  = rowptr[node0 + nl] + (t & 15);
    const int pe = permute[e];
    s_src[t] = colind[e];
    const float px = pseudo[(size_t)pe * 2 + 0];
    const float py = pseudo[(size_t)pe * 2 + 1];
#pragma unroll
    for (int k = 0; k < KK; ++k) {
      const float dx = (px - mx[k]) * sx[k];
      const float dy = (py - my[k]) * sy[k];
      s_w[t][k] = __expf(-0.5f * (dx * dx + dy * dy));
    }
  }
  __syncthreads();

  const int nl = tid >> 2;    // local node 0..31
  const int f8 = tid & 3;     // features f8*8 .. f8*8+7

  float acc[8];
  {
    const float4 b0 = *(const float4*)&bias[f8 * 8];
    const float4 b1 = *(const float4*)&bias[f8 * 8 + 4];
    acc[0] = b0.x; acc[1] = b0.y; acc[2] = b0.z; acc[3] = b0.w;
    acc[4] = b1.x; acc[5] = b1.y; acc[6] = b1.z; acc[7] = b1.w;
  }

  const int tbase = nl * 16;
  const char* nfb = (const char*)nf + f8 * 16;

#pragma unroll
  for (int i = 0; i < DEG; ++i) {
    const int t = tbase + ((i + nl) & 15);   // rotate: conflict-free LDS reads
    const char* base = nfb + s_src[t] * (JDIM * 2);
    const uint4 u0 = *(const uint4*)(base);
    const uint4 u1 = *(const uint4*)(base + 64);
    const uint4 u2 = *(const uint4*)(base + 128);
    const uint4 u3 = *(const uint4*)(base + 192);
    const float4 w4 = *(const float4*)&s_w[t][0];

    acc[0] += w4.x * __uint_as_float(u0.x << 16);
    acc[1] += w4.x * __uint_as_float(u0.x & 0xffff0000u);
    acc[2] += w4.x * __uint_as_float(u0.y << 16);
    acc[3] += w4.x * __uint_as_float(u0.y & 0xffff0000u);
    acc[4] += w4.x * __uint_as_float(u0.z << 16);
    acc[5] += w4.x * __uint_as_float(u0.z & 0xffff0000u);
    acc[6] += w4.x * __uint_as_float(u0.w << 16);
    acc[7] += w4.x * __uint_as_float(u0.w & 0xffff0000u);

    acc[0] += w4.y * __uint_as_float(u1.x << 16);
    acc[1] += w4.y * __uint_as_float(u1.x & 0xffff0000u);
    acc[2] += w4.y * __uint_as_float(u1.y << 16);
    acc[3] += w4.y * __uint_as_float(u1.y & 0xffff0000u);
    acc[4] += w4.y * __uint_as_float(u1.z << 16);
    acc[5] += w4.y * __uint_as_float(u1.z & 0xffff0000u);
    acc[6] += w4.y * __uint_as_float(u1.w << 16);
    acc[7] += w4.y * __uint_as_float(u1.w & 0xffff0000u);

    acc[0] += w4.z * __uint_as_float(u2.x << 16);
    acc[1] += w4.z * __uint_as_float(u2.x & 0xffff0000u);
    acc[2] += w4.z * __uint_as_float(u2.y << 16);
    acc[3] += w4.z * __uint_as_float(u2.y & 0xffff0000u);
    acc[4] += w4.z * __uint_as_float(u2.z << 16);
    acc[5] += w4.z * __uint_as_float(u2.z & 0xffff0000u);
    acc[6] += w4.z * __uint_as_float(u2.w << 16);
    acc[7] += w4.z * __uint_as_float(u2.w & 0xffff0000u);

    acc[0] += w4.w * __uint_as_float(u3.x << 16);
    acc[1] += w4.w * __uint_as_float(u3.x & 0xffff0000u);
    acc[2] += w4.w * __uint_as_float(u3.y << 16);
    acc[3] += w4.w * __uint_as_float(u3.y & 0xffff0000u);
    acc[4] += w4.w * __uint_as_float(u3.z << 16);
    acc[5] += w4.w * __uint_as_float(u3.z & 0xffff0000u);
    acc[6] += w4.w * __uint_as_float(u3.w << 16);
    acc[7] += w4.w * __uint_as_float(u3.w & 0xffff0000u);
  }

  float4 o0 = {acc[0], acc[1], acc[2], acc[3]};
  float4 o1 = {acc[4], acc[5], acc[6], acc[7]};
  float* op = out + (size_t)(node0 + nl) * OUT_F + f8 * 8;
  *(float4*)(op)     = o0;
  *(float4*)(op + 4) = o1;
}

extern "C" void kernel_launch(void* const* d_in, const int* in_sizes, int n_in,
                              void* d_out, int out_size, void* d_ws, size_t ws_size,
                              hipStream_t stream) {
  const int*   rowptr    = (const int*)d_in[0];
  const int*   colind    = (const int*)d_in[1];
  // d_in[2] colptr, d_in[3] rowind: backward-only, unused in fwd
  const int*   permute   = (const int*)d_in[4];
  const float* feat      = (const float*)d_in[5];
  const float* pseudo    = (const float*)d_in[6];
  const float* fc_w      = (const float*)d_in[7];
  const float* mu        = (const float*)d_in[8];
  const float* inv_sigma = (const float*)d_in[9];
  const float* bias      = (const float*)d_in[10];
  float* out = (float*)d_out;

  unsigned short* nf   = (unsigned short*)d_ws;                        // 25.6 MB
  unsigned short* wcvt = (unsigned short*)((char*)d_ws + (26u << 20)); // 32 KB

  // P: fc_w fp32 -> bf16, fragment order (2048 threads)
  gmm_cvt_w<<<8, 256, 0, stream>>>(fc_w, wcvt);
  // A: 3125 32-node tiles, 4 waves/block -> 782 blocks
  gmm_fc_mfma<<<(NN / 32 + 3) / 4, 256, 0, stream>>>(feat, wcvt, nf);
  // B: 32 nodes/block -> 3125 blocks, 128 thr
  gmm_edge_gather<<<NN / 32, 128, 0, stream>>>(
      rowptr, colind, permute, pseudo, mu, inv_sigma, bias, nf, out);
}

// Round 6
// 194.441 us; speedup vs baseline: 1.2477x; 1.2477x over previous
//
#include <hip/hip_runtime.h>

#define NN     100000
#define DEG    16
#define IN_F   128
#define OUT_F  32
#define KK     4
#define JDIM   (KK * OUT_F)   // 128

typedef __attribute__((ext_vector_type(8))) short short8;     // 8 bf16 = 4 VGPR
typedef __attribute__((ext_vector_type(4))) short short4v;    // 4 bf16 = 8 B
typedef __attribute__((ext_vector_type(4))) float floatx4;    // MFMA C/D

// fp32 -> bf16 bits, round-to-nearest-even (inputs are finite normals)
static __device__ __forceinline__ unsigned short f2bf(float f) {
  unsigned int u = __builtin_bit_cast(unsigned int, f);
  u += 0x7fffu + ((u >> 16) & 1u);
  return (unsigned short)(u >> 16);
}

// ---------------------------------------------------------------------------
// Kernel P: fc_w (fp32, [128][128]) -> bf16 in MFMA A-fragment order.
// Slot g = (s*8+t)*64 + q*16 + c holds fc_w[t*16+c][s*32+q*8 .. +7]:
// kernel A's (s,t) fragment is slot (s*8+t)*64 + lane, 16 B, coalesced.
// ---------------------------------------------------------------------------
__global__ __launch_bounds__(256) void gmm_cvt_w(
    const float* __restrict__ fc_w, unsigned short* __restrict__ wcvt)
{
  const int g = blockIdx.x * 256 + threadIdx.x;   // 0..2047
  const int c = g & 15, q = (g >> 4) & 3, t = (g >> 6) & 7, s = g >> 9;
  const float* src = fc_w + (size_t)(t * 16 + c) * IN_F + s * 32 + q * 8;
  const float4 f0 = *(const float4*)src;
  const float4 f1 = *(const float4*)(src + 4);
  short8 v;
  v[0] = (short)f2bf(f0.x); v[1] = (short)f2bf(f0.y);
  v[2] = (short)f2bf(f0.z); v[3] = (short)f2bf(f0.w);
  v[4] = (short)f2bf(f1.x); v[5] = (short)f2bf(f1.y);
  v[6] = (short)f2bf(f1.z); v[7] = (short)f2bf(f1.w);
  *(short8*)(wcvt + (size_t)g * 8) = v;
}

// ---------------------------------------------------------------------------
// Kernel A (MFMA): nf_bf16[m][j] = sum_i feat[m][i] * fc_w[j][i]
// One wave per 32-node m-tile, 4 waves/block. W (32 KB, fragment order) is
// staged ONCE per block into LDS -> fragment reads are ds_read_b128, no L2
// latency in the MFMA loop. All 16 feat float4 loads issued up front
// (16-deep MLP, one latency exposure). Grid (~3 blocks/CU) limits occupancy,
// so extra VGPR for the feat batch is free (round-5 lesson: never force
// spills; here no launch_bounds minimum).
// D element r of acc[g][t]: node = m0+g*16+c, j = t*16+q*4+r -> 8 B stores.
// ---------------------------------------------------------------------------
__global__ __launch_bounds__(256) void gmm_fc_mfma(
    const float* __restrict__ feat, const unsigned short* __restrict__ wcvt,
    unsigned short* __restrict__ nf)
{
  __shared__ uint4 s_wfrag[2048];   // 32 KB: slot g = (s*8+t)*64 + lane

  const int tid  = threadIdx.x;
  const int lane = tid & 63;
  const int wv   = tid >> 6;

  // stage W: 8 x 256 coalesced uint4 copies (all threads, incl. tail waves)
  const uint4* wsrc = (const uint4*)wcvt;
#pragma unroll
  for (int r = 0; r < 8; ++r)
    s_wfrag[tid + r * 256] = wsrc[tid + r * 256];
  __syncthreads();

  const int tile = blockIdx.x * 4 + wv;            // 32-node tile id
  if (tile * 32 >= NN) return;                     // NN % 32 == 0: full tiles
  const int m0 = tile * 32;
  const int c  = lane & 15;
  const int q  = lane >> 4;

  // batch-load all feat inputs for this wave: 2 rows x 4 s x 2 float4
  const float* frow0 = feat + (size_t)(m0 + c) * IN_F + q * 8;
  const float* frow1 = frow0 + (size_t)16 * IN_F;
  float4 fr[2][4][2];
#pragma unroll
  for (int s = 0; s < 4; ++s) {
    fr[0][s][0] = *(const float4*)(frow0 + s * 32);
    fr[0][s][1] = *(const float4*)(frow0 + s * 32 + 4);
    fr[1][s][0] = *(const float4*)(frow1 + s * 32);
    fr[1][s][1] = *(const float4*)(frow1 + s * 32 + 4);
  }

  // convert to bf16 B-fragments
  short8 bv[2][4];
#pragma unroll
  for (int g = 0; g < 2; ++g) {
#pragma unroll
    for (int s = 0; s < 4; ++s) {
      const float4 b0 = fr[g][s][0];
      const float4 b1 = fr[g][s][1];
      short8 v;
      v[0] = (short)f2bf(b0.x); v[1] = (short)f2bf(b0.y);
      v[2] = (short)f2bf(b0.z); v[3] = (short)f2bf(b0.w);
      v[4] = (short)f2bf(b1.x); v[5] = (short)f2bf(b1.y);
      v[6] = (short)f2bf(b1.z); v[7] = (short)f2bf(b1.w);
      bv[g][s] = v;
    }
  }

  floatx4 acc[2][8];
#pragma unroll
  for (int g = 0; g < 2; ++g)
#pragma unroll
    for (int t = 0; t < 8; ++t) acc[g][t] = (floatx4){0.f, 0.f, 0.f, 0.f};

  const short8* wlds = (const short8*)s_wfrag;
#pragma unroll
  for (int s = 0; s < 4; ++s) {
#pragma unroll
    for (int t = 0; t < 8; ++t) {
      const short8 av = wlds[(s * 8 + t) * 64 + lane];
      acc[0][t] = __builtin_amdgcn_mfma_f32_16x16x32_bf16(av, bv[0][s], acc[0][t], 0, 0, 0);
      acc[1][t] = __builtin_amdgcn_mfma_f32_16x16x32_bf16(av, bv[1][s], acc[1][t], 0, 0, 0);
    }
  }

#pragma unroll
  for (int g = 0; g < 2; ++g) {
#pragma unroll
    for (int t = 0; t < 8; ++t) {
      short4v p;
      p[0] = (short)f2bf(acc[g][t][0]); p[1] = (short)f2bf(acc[g][t][1]);
      p[2] = (short)f2bf(acc[g][t][2]); p[3] = (short)f2bf(acc[g][t][3]);
      *(short4v*)(nf + (size_t)(m0 + g * 16 + c) * JDIM + t * 16 + q * 4) = p;
    }
  }
}

// ---------------------------------------------------------------------------
// Kernel B (round-3 verbatim — measured 63 µs ≈ 92% of the ~3.4 TB/s fabric
// ceiling for this random-64B gather; round-4 ILP pipeline and round-5
// forced-occupancy variants both regressed — see session journal).
// out[i][f] = bias[f] + sum_{e in row i} sum_k w[e,k]*nf[src_e][k*32+f]
// Block = 256 thr = 64 nodes x 4 lanes (8 features each, uint4 gathers,
// 4 lanes x 16B = 64B per (src,k)). 1024 edges staged in LDS.
// Edge read order rotated by local node id -> LDS bank-conflict-free.
// ---------------------------------------------------------------------------
__global__ __launch_bounds__(256) void gmm_edge_gather(
    const int* __restrict__ rowptr, const int* __restrict__ colind,
    const int* __restrict__ permute, const float* __restrict__ pseudo,
    const float* __restrict__ mu, const float* __restrict__ inv_sigma,
    const float* __restrict__ bias, const unsigned short* __restrict__ nf,
    float* __restrict__ out)
{
  __shared__ int   s_src[1024];      // 4 KB
  __shared__ float s_w[1024][4];     // 16 KB

  const int tid    = threadIdx.x;
  const int node0  = blockIdx.x * 64;
  const int nvalid = (NN - node0 < 64) ? (NN - node0) : 64;

  float mx[KK], my[KK], sx[KK], sy[KK];
#pragma unroll
  for (int k = 0; k < KK; ++k) {
    mx[k] = mu[k * 2 + 0];
    my[k] = mu[k * 2 + 1];
    sx[k] = inv_sigma[k * 2 + 0];
    sy[k] = inv_sigma[k * 2 + 1];
  }

  // stage 1024 edges (4 per thread): src id + 4 gaussian weights
#pragma unroll
  for (int r = 0; r < 4; ++r) {
    const int t  = tid + r * 256;
    const int nl = t >> 4;
    if (nl < nvalid) {
      const int e   = rowptr[node0 + nl] + (t & 15);
      const int pe  = permute[e];
      s_src[t] = colind[e];
      const float px = pseudo[(size_t)pe * 2 + 0];
      const float py = pseudo[(size_t)pe * 2 + 1];
#pragma unroll
      for (int k = 0; k < KK; ++k) {
        const float dx = (px - mx[k]) * sx[k];
        const float dy = (py - my[k]) * sy[k];
        s_w[t][k] = __expf(-0.5f * (dx * dx + dy * dy));
      }
    }
  }
  __syncthreads();

  const int nl = tid >> 2;    // local node 0..63
  const int f8 = tid & 3;     // features f8*8 .. f8*8+7
  if (nl >= nvalid) return;

  float acc[8];
  {
    const float4 b0 = *(const float4*)&bias[f8 * 8];
    const float4 b1 = *(const float4*)&bias[f8 * 8 + 4];
    acc[0] = b0.x; acc[1] = b0.y; acc[2] = b0.z; acc[3] = b0.w;
    acc[4] = b1.x; acc[5] = b1.y; acc[6] = b1.z; acc[7] = b1.w;
  }

  const int tbase = nl * 16;
#pragma unroll
  for (int i = 0; i < DEG; ++i) {
    const int e = (i + nl) & 15;          // rotate: conflict-free LDS reads
    const int t = tbase + e;
    const int src = s_src[t];
    const float4 w4 = *(const float4*)&s_w[t][0];
    const float wv[4] = {w4.x, w4.y, w4.z, w4.w};
    const unsigned short* row = nf + (size_t)src * JDIM + f8 * 8;
#pragma unroll
    for (int k = 0; k < KK; ++k) {
      const uint4 v = *(const uint4*)(row + k * 32);
      const float wk = wv[k];
      acc[0] += wk * __uint_as_float(v.x << 16);
      acc[1] += wk * __uint_as_float(v.x & 0xffff0000u);
      acc[2] += wk * __uint_as_float(v.y << 16);
      acc[3] += wk * __uint_as_float(v.y & 0xffff0000u);
      acc[4] += wk * __uint_as_float(v.z << 16);
      acc[5] += wk * __uint_as_float(v.z & 0xffff0000u);
      acc[6] += wk * __uint_as_float(v.w << 16);
      acc[7] += wk * __uint_as_float(v.w & 0xffff0000u);
    }
  }

  float4 o0 = {acc[0], acc[1], acc[2], acc[3]};
  float4 o1 = {acc[4], acc[5], acc[6], acc[7]};
  float* op = out + (size_t)(node0 + nl) * OUT_F + f8 * 8;
  *(float4*)(op)     = o0;
  *(float4*)(op + 4) = o1;
}

extern "C" void kernel_launch(void* const* d_in, const int* in_sizes, int n_in,
                              void* d_out, int out_size, void* d_ws, size_t ws_size,
                              hipStream_t stream) {
  const int*   rowptr    = (const int*)d_in[0];
  const int*   colind    = (const int*)d_in[1];
  // d_in[2] colptr, d_in[3] rowind: backward-only, unused in fwd
  const int*   permute   = (const int*)d_in[4];
  const float* feat      = (const float*)d_in[5];
  const float* pseudo    = (const float*)d_in[6];
  const float* fc_w      = (const float*)d_in[7];
  const float* mu        = (const float*)d_in[8];
  const float* inv_sigma = (const float*)d_in[9];
  const float* bias      = (const float*)d_in[10];
  float* out = (float*)d_out;

  unsigned short* nf   = (unsigned short*)d_ws;                        // 25.6 MB
  unsigned short* wcvt = (unsigned short*)((char*)d_ws + (26u << 20)); // 32 KB

  // P: fc_w fp32 -> bf16, fragment order (2048 threads)
  gmm_cvt_w<<<8, 256, 0, stream>>>(fc_w, wcvt);
  // A: 3125 32-node tiles, 4 waves/block -> 782 blocks
  gmm_fc_mfma<<<(NN / 32 + 3) / 4, 256, 0, stream>>>(feat, wcvt, nf);
  // B: 64 nodes/block -> 1563 blocks
  gmm_edge_gather<<<(NN + 63) / 64, 256, 0, stream>>>(
      rowptr, colind, permute, pseudo, mu, inv_sigma, bias, nf, out);
}

// Round 7
// 193.326 us; speedup vs baseline: 1.2549x; 1.0058x over previous
//
#include <hip/hip_runtime.h>

#define NN     100000
#define DEG    16
#define IN_F   128
#define OUT_F  32
#define KK     4
#define JDIM   (KK * OUT_F)   // 128
#define TRS    70             // transpose-buffer row stride in shorts (pad vs 64)

typedef __attribute__((ext_vector_type(8))) short short8;     // 8 bf16 = 4 VGPR
typedef __attribute__((ext_vector_type(4))) short short4v;    // 4 bf16 = 8 B
typedef __attribute__((ext_vector_type(4))) float floatx4;    // MFMA C/D

// fp32 -> bf16 bits, round-to-nearest-even (inputs are finite normals)
static __device__ __forceinline__ unsigned short f2bf(float f) {
  unsigned int u = __builtin_bit_cast(unsigned int, f);
  u += 0x7fffu + ((u >> 16) & 1u);
  return (unsigned short)(u >> 16);
}

// ---------------------------------------------------------------------------
// Kernel P: fc_w (fp32, [128][128]) -> bf16 in MFMA A-fragment order.
// Slot g = (s*8+t)*64 + q*16 + c holds fc_w[t*16+c][s*32+q*8 .. +7]:
// kernel A's (s,t) fragment is slot (s*8+t)*64 + lane, 16 B, coalesced.
// ---------------------------------------------------------------------------
__global__ __launch_bounds__(256) void gmm_cvt_w(
    const float* __restrict__ fc_w, unsigned short* __restrict__ wcvt)
{
  const int g = blockIdx.x * 256 + threadIdx.x;   // 0..2047
  const int c = g & 15, q = (g >> 4) & 3, t = (g >> 6) & 7, s = g >> 9;
  const float* src = fc_w + (size_t)(t * 16 + c) * IN_F + s * 32 + q * 8;
  const float4 f0 = *(const float4*)src;
  const float4 f1 = *(const float4*)(src + 4);
  short8 v;
  v[0] = (short)f2bf(f0.x); v[1] = (short)f2bf(f0.y);
  v[2] = (short)f2bf(f0.z); v[3] = (short)f2bf(f0.w);
  v[4] = (short)f2bf(f1.x); v[5] = (short)f2bf(f1.y);
  v[6] = (short)f2bf(f1.z); v[7] = (short)f2bf(f1.w);
  *(short8*)(wcvt + (size_t)g * 8) = v;
}

// ---------------------------------------------------------------------------
// Kernel A (MFMA): nf_bf16[m][j] = sum_i feat[m][i] * fc_w[j][i]
// One wave per 32-node m-tile, 4 waves/block. W (32 KB, fragment order)
// staged once per block into LDS. All 16 feat float4 loads issued up front.
// NEW (round 7): LDS-transpose epilogue — D's native layout only gives 8 B
// of contiguous j per lane (round-6 A wrote nf in 8 B granules, 16 lines
// per store instr); route acc through a wave-private padded LDS buffer and
// store uint4 with 128 B-contiguous granules. No barrier needed (wave-
// private; ds ops wave-ordered). LDS total 49.9 KB -> 3 blocks/CU.
// ---------------------------------------------------------------------------
__global__ __launch_bounds__(256) void gmm_fc_mfma(
    const float* __restrict__ feat, const unsigned short* __restrict__ wcvt,
    unsigned short* __restrict__ nf)
{
  __shared__ uint4 s_wfrag[2048];                    // 32 KB
  __shared__ unsigned short s_tr[4][32 * TRS];       // 4 x 4.4 KB

  const int tid  = threadIdx.x;
  const int lane = tid & 63;
  const int wv   = tid >> 6;

  // stage W: 8 x 256 coalesced uint4 copies
  const uint4* wsrc = (const uint4*)wcvt;
#pragma unroll
  for (int r = 0; r < 8; ++r)
    s_wfrag[tid + r * 256] = wsrc[tid + r * 256];
  __syncthreads();

  const int tile = blockIdx.x * 4 + wv;            // 32-node tile id
  if (tile * 32 >= NN) return;                     // NN % 32 == 0: full tiles
  const int m0 = tile * 32;
  const int c  = lane & 15;
  const int q  = lane >> 4;

  // batch-load all feat inputs for this wave (16-deep MLP, one exposure)
  const float* frow0 = feat + (size_t)(m0 + c) * IN_F + q * 8;
  const float* frow1 = frow0 + (size_t)16 * IN_F;
  float4 fr[2][4][2];
#pragma unroll
  for (int s = 0; s < 4; ++s) {
    fr[0][s][0] = *(const float4*)(frow0 + s * 32);
    fr[0][s][1] = *(const float4*)(frow0 + s * 32 + 4);
    fr[1][s][0] = *(const float4*)(frow1 + s * 32);
    fr[1][s][1] = *(const float4*)(frow1 + s * 32 + 4);
  }

  // convert to bf16 B-fragments
  short8 bv[2][4];
#pragma unroll
  for (int g = 0; g < 2; ++g) {
#pragma unroll
    for (int s = 0; s < 4; ++s) {
      const float4 b0 = fr[g][s][0];
      const float4 b1 = fr[g][s][1];
      short8 v;
      v[0] = (short)f2bf(b0.x); v[1] = (short)f2bf(b0.y);
      v[2] = (short)f2bf(b0.z); v[3] = (short)f2bf(b0.w);
      v[4] = (short)f2bf(b1.x); v[5] = (short)f2bf(b1.y);
      v[6] = (short)f2bf(b1.z); v[7] = (short)f2bf(b1.w);
      bv[g][s] = v;
    }
  }

  floatx4 acc[2][8];
#pragma unroll
  for (int g = 0; g < 2; ++g)
#pragma unroll
    for (int t = 0; t < 8; ++t) acc[g][t] = (floatx4){0.f, 0.f, 0.f, 0.f};

  const short8* wlds = (const short8*)s_wfrag;
#pragma unroll
  for (int s = 0; s < 4; ++s) {
#pragma unroll
    for (int t = 0; t < 8; ++t) {
      const short8 av = wlds[(s * 8 + t) * 64 + lane];
      acc[0][t] = __builtin_amdgcn_mfma_f32_16x16x32_bf16(av, bv[0][s], acc[0][t], 0, 0, 0);
      acc[1][t] = __builtin_amdgcn_mfma_f32_16x16x32_bf16(av, bv[1][s], acc[1][t], 0, 0, 0);
    }
  }

  // Epilogue: two j-halves (th), wave-private transpose buffer.
  // acc[g][t][r] -> node row g*16+c, j = t*16 + q*4 + r.
  unsigned short* tr = &s_tr[wv][0];
#pragma unroll
  for (int th = 0; th < 2; ++th) {
#pragma unroll
    for (int g = 0; g < 2; ++g) {
#pragma unroll
      for (int tt = 0; tt < 4; ++tt) {
        const int t = th * 4 + tt;
        short4v p;
        p[0] = (short)f2bf(acc[g][t][0]); p[1] = (short)f2bf(acc[g][t][1]);
        p[2] = (short)f2bf(acc[g][t][2]); p[3] = (short)f2bf(acc[g][t][3]);
        *(short4v*)&tr[(g * 16 + c) * TRS + tt * 16 + q * 4] = p;
      }
    }
    // read back + store: 4 uint4/lane, 8 rows x 128 B contiguous per instr
#pragma unroll
    for (int jj = 0; jj < 4; ++jj) {
      const int chunk = jj * 64 + lane;       // 16 B chunks, 256 total
      const int row = chunk >> 3;             // node row 0..31
      const int co  = chunk & 7;              // chunk within 128 B half-row
      const uint4 v = *(const uint4*)&tr[row * TRS + co * 8];
      *(uint4*)(nf + (size_t)(m0 + row) * JDIM + th * 64 + co * 8) = v;
    }
  }
}

// ---------------------------------------------------------------------------
// Kernel B (round-3 verbatim — measured 63-65 µs at the ~3.2-3.4 TB/s
// fabric/L3 ceiling for random-64B gathers; invariant across occupancy
// 18/26/52% (rounds 3/4/5) -> structural. Do not re-tune.
// out[i][f] = bias[f] + sum_{e in row i} sum_k w[e,k]*nf[src_e][k*32+f]
// Block = 256 thr = 64 nodes x 4 lanes (8 features each, uint4 gathers,
// 4 lanes x 16B = 64B per (src,k)). 1024 edges staged in LDS.
// Edge read order rotated by local node id -> LDS bank-conflict-free.
// ---------------------------------------------------------------------------
__global__ __launch_bounds__(256) void gmm_edge_gather(
    const int* __restrict__ rowptr, const int* __restrict__ colind,
    const int* __restrict__ permute, const float* __restrict__ pseudo,
    const float* __restrict__ mu, const float* __restrict__ inv_sigma,
    const float* __restrict__ bias, const unsigned short* __restrict__ nf,
    float* __restrict__ out)
{
  __shared__ int   s_src[1024];      // 4 KB
  __shared__ float s_w[1024][4];     // 16 KB

  const int tid    = threadIdx.x;
  const int node0  = blockIdx.x * 64;
  const int nvalid = (NN - node0 < 64) ? (NN - node0) : 64;

  float mx[KK], my[KK], sx[KK], sy[KK];
#pragma unroll
  for (int k = 0; k < KK; ++k) {
    mx[k] = mu[k * 2 + 0];
    my[k] = mu[k * 2 + 1];
    sx[k] = inv_sigma[k * 2 + 0];
    sy[k] = inv_sigma[k * 2 + 1];
  }

  // stage 1024 edges (4 per thread): src id + 4 gaussian weights
#pragma unroll
  for (int r = 0; r < 4; ++r) {
    const int t  = tid + r * 256;
    const int nl = t >> 4;
    if (nl < nvalid) {
      const int e   = rowptr[node0 + nl] + (t & 15);
      const int pe  = permute[e];
      s_src[t] = colind[e];
      const float px = pseudo[(size_t)pe * 2 + 0];
      const float py = pseudo[(size_t)pe * 2 + 1];
#pragma unroll
      for (int k = 0; k < KK; ++k) {
        const float dx = (px - mx[k]) * sx[k];
        const float dy = (py - my[k]) * sy[k];
        s_w[t][k] = __expf(-0.5f * (dx * dx + dy * dy));
      }
    }
  }
  __syncthreads();

  const int nl = tid >> 2;    // local node 0..63
  const int f8 = tid & 3;     // features f8*8 .. f8*8+7
  if (nl >= nvalid) return;

  float acc[8];
  {
    const float4 b0 = *(const float4*)&bias[f8 * 8];
    const float4 b1 = *(const float4*)&bias[f8 * 8 + 4];
    acc[0] = b0.x; acc[1] = b0.y; acc[2] = b0.z; acc[3] = b0.w;
    acc[4] = b1.x; acc[5] = b1.y; acc[6] = b1.z; acc[7] = b1.w;
  }

  const int tbase = nl * 16;
#pragma unroll
  for (int i = 0; i < DEG; ++i) {
    const int e = (i + nl) & 15;          // rotate: conflict-free LDS reads
    const int t = tbase + e;
    const int src = s_src[t];
    const float4 w4 = *(const float4*)&s_w[t][0];
    const float wv[4] = {w4.x, w4.y, w4.z, w4.w};
    const unsigned short* row = nf + (size_t)src * JDIM + f8 * 8;
#pragma unroll
    for (int k = 0; k < KK; ++k) {
      const uint4 v = *(const uint4*)(row + k * 32);
      const float wk = wv[k];
      acc[0] += wk * __uint_as_float(v.x << 16);
      acc[1] += wk * __uint_as_float(v.x & 0xffff0000u);
      acc[2] += wk * __uint_as_float(v.y << 16);
      acc[3] += wk * __uint_as_float(v.y & 0xffff0000u);
      acc[4] += wk * __uint_as_float(v.z << 16);
      acc[5] += wk * __uint_as_float(v.z & 0xffff0000u);
      acc[6] += wk * __uint_as_float(v.w << 16);
      acc[7] += wk * __uint_as_float(v.w & 0xffff0000u);
    }
  }

  float4 o0 = {acc[0], acc[1], acc[2], acc[3]};
  float4 o1 = {acc[4], acc[5], acc[6], acc[7]};
  float* op = out + (size_t)(node0 + nl) * OUT_F + f8 * 8;
  *(float4*)(op)     = o0;
  *(float4*)(op + 4) = o1;
}

extern "C" void kernel_launch(void* const* d_in, const int* in_sizes, int n_in,
                              void* d_out, int out_size, void* d_ws, size_t ws_size,
                              hipStream_t stream) {
  const int*   rowptr    = (const int*)d_in[0];
  const int*   colind    = (const int*)d_in[1];
  // d_in[2] colptr, d_in[3] rowind: backward-only, unused in fwd
  const int*   permute   = (const int*)d_in[4];
  const float* feat      = (const float*)d_in[5];
  const float* pseudo    = (const float*)d_in[6];
  const float* fc_w      = (const float*)d_in[7];
  const float* mu        = (const float*)d_in[8];
  const float* inv_sigma = (const float*)d_in[9];
  const float* bias      = (const float*)d_in[10];
  float* out = (float*)d_out;

  unsigned short* nf   = (unsigned short*)d_ws;                        // 25.6 MB
  unsigned short* wcvt = (unsigned short*)((char*)d_ws + (26u << 20)); // 32 KB

  // P: fc_w fp32 -> bf16, fragment order (2048 threads)
  gmm_cvt_w<<<8, 256, 0, stream>>>(fc_w, wcvt);
  // A: 3125 32-node tiles, 4 waves/block -> 782 blocks
  gmm_fc_mfma<<<(NN / 32 + 3) / 4, 256, 0, stream>>>(feat, wcvt, nf);
  // B: 64 nodes/block -> 1563 blocks
  gmm_edge_gather<<<(NN + 63) / 64, 256, 0, stream>>>(
      rowptr, colind, permute, pseudo, mu, inv_sigma, bias, nf, out);
}